// Round 7
// baseline (60.054 us; speedup 1.0000x reference)
//
#include <hip/hip_runtime.h>
#include <math.h>

constexpr int T_LEN  = 8192;   // per-row length (== TREF)
constexpr int B_ROWS = 4096;
constexpr int NB     = 49;     // NBINS - 1 bins
constexpr int NC     = 32;     // histogram replicas (copy = tid & 31)
constexpr int HDIM   = 32;
constexpr int FBINS  = 8192;   // fine CDF resolution
constexpr float EPSF = 1e-10f;

// ws layout (float units): [0]=rmin [1]=rmax ; int cdf[FBINS+1] at +8 ;
// float binned[T_LEN] at +8208 ; float2 mm[B_ROWS] at +16400
constexpr int WS_CDF_OFF    = 8;
constexpr int WS_BINNED_OFF = 8208;
constexpr int WS_MM_OFF     = 16400;   // byte off 65600, 8B-aligned

// LDS pad: +1 word per 32 so per-thread 32-contiguous chunks are conflict-free
#define HP(i) ((i) + ((i) >> 5))

// LDS-only block sync: waits DS ops, leaves global loads in flight.
__device__ __forceinline__ void sync_lds() {
    asm volatile("s_waitcnt lgkmcnt(0)" ::: "memory");
    __builtin_amdgcn_s_barrier();
    __builtin_amdgcn_sched_barrier(0);
}

// -------- kernel 1 (1 block): ref min/max + fine histogram + CDF + scatter ----
__global__ __launch_bounds__(256)
void ref_cdf_kernel(const float* __restrict__ ref, float* __restrict__ wsf) {
    __shared__ float sv[FBINS];          // 32 KB ref copy
    __shared__ int   hist[HP(FBINS)];    // padded fine histogram -> excl. scan
    __shared__ int   wsum[4];
    __shared__ float rmn4[4], rmx4[4];
    const int tid  = threadIdx.x;
    const int lane = tid & 63;
    const int wave = tid >> 6;

    const float4* r4 = (const float4*)ref;
    float4* sv4 = (float4*)sv;
    float mn = 3.0e38f, mx = -3.0e38f;
    #pragma unroll
    for (int i = 0; i < 8; ++i) {
        float4 v = r4[tid + i * 256];
        sv4[tid + i * 256] = v;
        mn = fminf(mn, fminf(fminf(v.x, v.y), fminf(v.z, v.w)));
        mx = fmaxf(mx, fmaxf(fmaxf(v.x, v.y), fmaxf(v.z, v.w)));
    }
    for (int i = tid; i < HP(FBINS); i += 256) hist[i] = 0;
    #pragma unroll
    for (int off = 32; off > 0; off >>= 1) {
        mn = fminf(mn, __shfl_xor(mn, off));
        mx = fmaxf(mx, __shfl_xor(mx, off));
    }
    if (lane == 0) { rmn4[wave] = mn; rmx4[wave] = mx; }
    __syncthreads();
    const float rmin = fminf(fminf(rmn4[0], rmn4[1]), fminf(rmn4[2], rmn4[3]));
    const float rmax = fmaxf(fmaxf(rmx4[0], rmx4[1]), fmaxf(rmx4[2], rmx4[3]));
    const float finv = (float)FBINS / (rmax - rmin);

    // fine histogram ((x-rmin)*finv >= 0 -> trunc == floor)
    for (int i = tid; i < FBINS; i += 256) {
        int fb = min(max((int)((sv[i] - rmin) * finv), 0), FBINS - 1);
        atomicAdd(&hist[HP(fb)], 1);
    }
    __syncthreads();

    // exclusive scan: per-thread 32-chunk + wave shuffle-scan + cross-wave fix
    const int base = tid * 32;
    int s = 0;
    #pragma unroll
    for (int j = 0; j < 32; ++j) {
        int h = hist[HP(base + j)]; hist[HP(base + j)] = s; s += h;
    }
    const int own = s;
    int incl = s;
    #pragma unroll
    for (int off = 1; off < 64; off <<= 1) {
        int t = __shfl_up(incl, off);
        if (lane >= off) incl += t;
    }
    if (lane == 63) wsum[wave] = incl;
    __syncthreads();
    int woff = 0;
    #pragma unroll
    for (int w = 0; w < 4; ++w) if (w < wave) woff += wsum[w];
    const int add = woff + incl - own;
    #pragma unroll
    for (int j = 0; j < 32; ++j) hist[HP(base + j)] += add;
    __syncthreads();

    int* cdf = (int*)(wsf + WS_CDF_OFF);
    for (int i = tid; i < FBINS; i += 256) cdf[i] = hist[HP(i)];
    if (tid == 0) { cdf[FBINS] = T_LEN; wsf[0] = rmin; wsf[1] = rmax; }
    __syncthreads();

    float* binned = wsf + WS_BINNED_OFF;
    for (int i = tid; i < FBINS; i += 256) {
        float x = sv[i];
        int fb = min(max((int)((x - rmin) * finv), 0), FBINS - 1);
        int pos = atomicAdd(&hist[HP(fb)], 1);
        binned[pos] = x;
    }
}

// -------- kernel 2: per-row min/max, one wave per row, pure stream ----------
__global__ __launch_bounds__(256)
void minmax_kernel(const float* __restrict__ cur, float2* __restrict__ mm) {
    const int lane = threadIdx.x & 63;
    const int wave = threadIdx.x >> 6;
    const int row  = blockIdx.x * 4 + wave;
    const float4* src = (const float4*)(cur + (size_t)row * T_LEN);
    float mn = 3.0e38f, mx = -3.0e38f;
    float4 c[16];
    #pragma unroll
    for (int i = 0; i < 16; ++i) c[i] = src[lane + i * 64];
    #pragma unroll
    for (int i = 0; i < 16; ++i) {
        mn = fminf(mn, fminf(fminf(c[i].x, c[i].y), fminf(c[i].z, c[i].w)));
        mx = fmaxf(mx, fmaxf(fmaxf(c[i].x, c[i].y), fmaxf(c[i].z, c[i].w)));
    }
    #pragma unroll
    for (int i = 0; i < 16; ++i) c[i] = src[lane + (16 + i) * 64];
    #pragma unroll
    for (int i = 0; i < 16; ++i) {
        mn = fminf(mn, fminf(fminf(c[i].x, c[i].y), fminf(c[i].z, c[i].w)));
        mx = fmaxf(mx, fmaxf(fmaxf(c[i].x, c[i].y), fmaxf(c[i].z, c[i].w)));
    }
    #pragma unroll
    for (int off = 32; off > 0; off >>= 1) {
        mn = fminf(mn, __shfl_xor(mn, off));
        mx = fmaxf(mx, __shfl_xor(mx, off));
    }
    if (lane == 0) mm[row] = make_float2(mn, mx);
}

// -------- kernel 3: binning + KL + MLP; lo/width known, bin-as-loads-land ----
__global__ __launch_bounds__(256)
void bin_kernel(const float* __restrict__ cur,
                const float* __restrict__ wsf,
                const float2* __restrict__ mm,
                const float* __restrict__ w1,
                const float* __restrict__ b1,
                const float* __restrict__ w2,
                const float* __restrict__ b2,
                float* __restrict__ kl_out,
                float* __restrict__ enc_out) {
    __shared__ unsigned hq[NC * NB];

    const int b    = blockIdx.x;
    const int tid  = threadIdx.x;
    const int lane = tid & 63;

    // issue all row loads first; they stay in flight across the LDS-only sync
    const float4* src = (const float4*)(cur + (size_t)b * T_LEN);
    float4 v[8];
    #pragma unroll
    for (int i = 0; i < 8; ++i) v[i] = src[tid + i * 256];

    for (int i = tid; i < NC * NB; i += 256) hq[i] = 0u;

    const float rmin = wsf[0], rmax = wsf[1];
    const float2 cmm = mm[b];
    const float lo = fminf(rmin, cmm.x);
    const float hi = fmaxf(rmax, cmm.y);
    const float width = (hi - lo) / (float)NB;
    sync_lds();                       // hq zeroed; global loads still in flight

    const float winv = 1.0f / width, nlw = -lo * winv;
    unsigned* myq = hq + (tid & (NC - 1)) * NB;
    #pragma unroll
    for (int i = 0; i < 8; ++i) {
        int i0 = min(max((int)fmaf(v[i].x, winv, nlw), 0), NB - 1);
        int i1 = min(max((int)fmaf(v[i].y, winv, nlw), 0), NB - 1);
        int i2 = min(max((int)fmaf(v[i].z, winv, nlw), 0), NB - 1);
        int i3 = min(max((int)fmaf(v[i].w, winv, nlw), 0), NB - 1);
        atomicAdd(&myq[i0], 1u); atomicAdd(&myq[i1], 1u);
        atomicAdd(&myq[i2], 1u); atomicAdd(&myq[i3], 1u);
    }
    sync_lds();

    // ---- tail on wave 0 ----
    if (tid < 64) {
        const bool act = lane < NB;
        const float inv = 1.0f / ((float)T_LEN * width);
        float p = 0.0f, q = 0.0f;
        if (act) {
            unsigned sq = 0u;
            #pragma unroll
            for (int c = 0; c < NC; ++c) sq += hq[c * NB + lane];
            q = (float)sq * inv + EPSF;
        }
        // reference cumulative counts C(k) via fine-CDF window + exact predicate
        int C = T_LEN;
        if (lane < NB - 1) {
            const float kp1  = (float)(lane + 1);
            const float finv = (float)FBINS / (rmax - rmin);
            const int* cdf = (const int*)(wsf + WS_CDF_OFF);
            const float* binned = wsf + WS_BINNED_OFF;
            const float t = fmaf(width, kp1, lo);
            int fb = (int)floorf((t - rmin) * finv);
            int a  = min(max(fb - 2, 0), FBINS);
            int bb = min(max(fb + 3, 0), FBINS);
            int ia = cdf[a], ib = cdf[bb];
            C = ia;
            for (int i = ia; i < ib; i += 4) {
                float x0 = binned[i];
                float x1 = (i + 1 < ib) ? binned[i + 1] : 3.0e38f;
                float x2 = (i + 2 < ib) ? binned[i + 2] : 3.0e38f;
                float x3 = (i + 3 < ib) ? binned[i + 3] : 3.0e38f;
                C += ((x0 - lo) / width < kp1) ? 1 : 0;
                C += ((x1 - lo) / width < kp1) ? 1 : 0;
                C += ((x2 - lo) / width < kp1) ? 1 : 0;
                C += ((x3 - lo) / width < kp1) ? 1 : 0;
            }
        }
        int Cprev = __shfl_up(C, 1);
        if (lane == 0) Cprev = 0;
        if (act) p = (float)(C - Cprev) * inv + EPSF;

        float P = p, Q = q;
        #pragma unroll
        for (int off = 32; off > 0; off >>= 1) {
            P += __shfl_xor(P, off);
            Q += __shfl_xor(Q, off);
        }
        float term = 0.0f;
        if (act) {
            const float pn = p / P;
            const float qn = q / Q;
            term = pn * logf(pn / qn);
        }
        #pragma unroll
        for (int off = 32; off > 0; off >>= 1) term += __shfl_xor(term, off);
        if (lane == 0) kl_out[b] = term;

        if (lane < HDIM) {
            float acc = b2[lane];
            #pragma unroll
            for (int t2 = 0; t2 < HDIM; ++t2) {
                float h = fmaxf(fmaf(term, w1[t2], b1[t2]), 0.0f);
                acc = fmaf(h, w2[lane * HDIM + t2], acc);
            }
            enc_out[(size_t)b * HDIM + lane] = acc;
        }
    }
}

extern "C" void kernel_launch(void* const* d_in, const int* in_sizes, int n_in,
                              void* d_out, int out_size, void* d_ws, size_t ws_size,
                              hipStream_t stream) {
    const float* cur = (const float*)d_in[0];
    const float* ref = (const float*)d_in[1];
    const float* w1  = (const float*)d_in[2];
    const float* b1  = (const float*)d_in[3];
    const float* w2  = (const float*)d_in[4];
    const float* b2  = (const float*)d_in[5];
    float* out = (float*)d_out;           // [0, B) = kl ; [B, B + B*H) = encoded
    float* wsf = (float*)d_ws;
    float2* mm = (float2*)(wsf + WS_MM_OFF);

    ref_cdf_kernel<<<1, 256, 0, stream>>>(ref, wsf);
    minmax_kernel<<<B_ROWS / 4, 256, 0, stream>>>(cur, mm);
    bin_kernel<<<B_ROWS, 256, 0, stream>>>(
        cur, wsf, mm, w1, b1, w2, b2, out, out + B_ROWS);
}

// Round 8
// 44.137 us; speedup vs baseline: 1.3606x; 1.3606x over previous
//
#include <hip/hip_runtime.h>
#include <math.h>

constexpr int T_LEN  = 8192;   // per-row length (== TREF)
constexpr int B_ROWS = 4096;
constexpr int NB     = 49;     // NBINS - 1 bins
constexpr int NC     = 32;     // histogram replicas (copy = lane & 31)
constexpr int HDIM   = 32;
constexpr int FBINS  = 8192;   // fine CDF resolution
constexpr float EPSF = 1e-10f;

// ws layout (float units): [0]=rmin [1]=rmax ; int cdf[FBINS+1] at +8 ;
// float binned[T_LEN] (counting-scattered ref) at +8208
constexpr int WS_CDF_OFF    = 8;
constexpr int WS_BINNED_OFF = 8208;

// LDS pad: +1 word per 32 so per-thread 32-contiguous chunks are conflict-free
#define HP(i) ((i) + ((i) >> 5))

// wave-local LDS fence: ensure all our DS ops completed before dependent reads
__device__ __forceinline__ void lds_fence() {
    asm volatile("s_waitcnt lgkmcnt(0)" ::: "memory");
    __builtin_amdgcn_sched_barrier(0);
}

// -------- kernel 1 (1 block): ref min/max + fine histogram + CDF + scatter ----
__global__ __launch_bounds__(256)
void ref_cdf_kernel(const float* __restrict__ ref, float* __restrict__ wsf) {
    __shared__ float sv[FBINS];          // 32 KB ref copy
    __shared__ int   hist[HP(FBINS)];    // padded fine histogram -> excl. scan
    __shared__ int   wsum[4];
    __shared__ float rmn4[4], rmx4[4];
    const int tid  = threadIdx.x;
    const int lane = tid & 63;
    const int wave = tid >> 6;

    const float4* r4 = (const float4*)ref;
    float4* sv4 = (float4*)sv;
    float mn = 3.0e38f, mx = -3.0e38f;
    #pragma unroll
    for (int i = 0; i < 8; ++i) {
        float4 v = r4[tid + i * 256];
        sv4[tid + i * 256] = v;
        mn = fminf(mn, fminf(fminf(v.x, v.y), fminf(v.z, v.w)));
        mx = fmaxf(mx, fmaxf(fmaxf(v.x, v.y), fmaxf(v.z, v.w)));
    }
    for (int i = tid; i < HP(FBINS); i += 256) hist[i] = 0;
    #pragma unroll
    for (int off = 32; off > 0; off >>= 1) {
        mn = fminf(mn, __shfl_xor(mn, off));
        mx = fmaxf(mx, __shfl_xor(mx, off));
    }
    if (lane == 0) { rmn4[wave] = mn; rmx4[wave] = mx; }
    __syncthreads();
    const float rmin = fminf(fminf(rmn4[0], rmn4[1]), fminf(rmn4[2], rmn4[3]));
    const float rmax = fmaxf(fmaxf(rmx4[0], rmx4[1]), fmaxf(rmx4[2], rmx4[3]));
    const float finv = (float)FBINS / (rmax - rmin);

    // fine histogram ((x-rmin)*finv >= 0 -> trunc == floor)
    for (int i = tid; i < FBINS; i += 256) {
        int fb = min(max((int)((sv[i] - rmin) * finv), 0), FBINS - 1);
        atomicAdd(&hist[HP(fb)], 1);
    }
    __syncthreads();

    // exclusive scan: per-thread 32-chunk + wave shuffle-scan + cross-wave fix
    const int base = tid * 32;
    int s = 0;
    #pragma unroll
    for (int j = 0; j < 32; ++j) {
        int h = hist[HP(base + j)]; hist[HP(base + j)] = s; s += h;
    }
    const int own = s;
    int incl = s;
    #pragma unroll
    for (int off = 1; off < 64; off <<= 1) {
        int t = __shfl_up(incl, off);
        if (lane >= off) incl += t;
    }
    if (lane == 63) wsum[wave] = incl;
    __syncthreads();
    int woff = 0;
    #pragma unroll
    for (int w = 0; w < 4; ++w) if (w < wave) woff += wsum[w];
    const int add = woff + incl - own;
    #pragma unroll
    for (int j = 0; j < 32; ++j) hist[HP(base + j)] += add;
    __syncthreads();

    int* cdf = (int*)(wsf + WS_CDF_OFF);
    for (int i = tid; i < FBINS; i += 256) cdf[i] = hist[HP(i)];
    if (tid == 0) { cdf[FBINS] = T_LEN; wsf[0] = rmin; wsf[1] = rmax; }
    __syncthreads();

    float* binned = wsf + WS_BINNED_OFF;
    for (int i = tid; i < FBINS; i += 256) {
        float x = sv[i];
        int fb = min(max((int)((x - rmin) * finv), 0), FBINS - 1);
        int pos = atomicAdd(&hist[HP(fb)], 1);
        binned[pos] = x;
    }
}

// -------- kernel 2: one ROW per 64-thread block; zero barriers --------------
// Each wave is a fully independent pipeline: 32 loads in flight -> minmax by
// shuffle -> 32-replica LDS histogram -> CDF-window ref counts -> KL -> MLP.
// Independent waves at different phases interleave on the CU, overlapping
// memory, VALU and DS pipes across rows.
__global__ __launch_bounds__(64, 3)
void kl_wave_kernel(const float* __restrict__ cur,
                    const float* __restrict__ wsf,
                    const float* __restrict__ w1,
                    const float* __restrict__ b1,
                    const float* __restrict__ w2,
                    const float* __restrict__ b2,
                    float* __restrict__ kl_out,
                    float* __restrict__ enc_out) {
    __shared__ unsigned hq[NC * NB];          // 6272 B, one wave's histogram

    const int lane = threadIdx.x;             // 0..63
    const int b    = blockIdx.x;
    const float4* src = (const float4*)(cur + (size_t)b * T_LEN);

    // issue the entire row: 32 independent 16B loads per lane
    float4 v[32];
    #pragma unroll
    for (int i = 0; i < 32; ++i) v[i] = src[lane + i * 64];

    // zero histogram + fetch ref range while loads are in flight
    #pragma unroll
    for (int i = 0; i < 25; ++i) {
        int idx = lane + i * 64;
        if (idx < NC * NB) hq[idx] = 0u;
    }
    const float rmin = wsf[0], rmax = wsf[1];

    // ---- min/max ----
    float mn = 3.0e38f, mx = -3.0e38f;
    #pragma unroll
    for (int i = 0; i < 32; ++i) {
        mn = fminf(mn, fminf(fminf(v[i].x, v[i].y), fminf(v[i].z, v[i].w)));
        mx = fmaxf(mx, fmaxf(fmaxf(v[i].x, v[i].y), fmaxf(v[i].z, v[i].w)));
    }
    #pragma unroll
    for (int off = 32; off > 0; off >>= 1) {
        mn = fminf(mn, __shfl_xor(mn, off));
        mx = fmaxf(mx, __shfl_xor(mx, off));
    }
    const float lo = fminf(rmin, mn);
    const float hi = fmaxf(rmax, mx);
    const float width = (hi - lo) / (float)NB;
    const float winv = 1.0f / width, nlw = -lo * winv;

    // ---- histogram (replica = lane & 31; 2 lanes/replica, 2-way is free) ----
    lds_fence();                               // init visible before atomics
    unsigned* myq = hq + (lane & (NC - 1)) * NB;
    #pragma unroll
    for (int i = 0; i < 32; ++i) {
        int i0 = min(max((int)fmaf(v[i].x, winv, nlw), 0), NB - 1);
        int i1 = min(max((int)fmaf(v[i].y, winv, nlw), 0), NB - 1);
        int i2 = min(max((int)fmaf(v[i].z, winv, nlw), 0), NB - 1);
        int i3 = min(max((int)fmaf(v[i].w, winv, nlw), 0), NB - 1);
        atomicAdd(&myq[i0], 1u); atomicAdd(&myq[i1], 1u);
        atomicAdd(&myq[i2], 1u); atomicAdd(&myq[i3], 1u);
    }
    lds_fence();                               // atomics done before readback

    // ---- tail: ref counts via fine-CDF window + KL + MLP, all on this wave --
    const bool act = lane < NB;
    const float inv = 1.0f / ((float)T_LEN * width);
    float p = 0.0f, q = 0.0f;
    if (act) {
        unsigned sq = 0u;
        #pragma unroll
        for (int c = 0; c < NC; ++c) sq += hq[c * NB + lane];
        q = (float)sq * inv + EPSF;
    }
    int C = T_LEN;
    if (lane < NB - 1) {
        const float kp1  = (float)(lane + 1);
        const float finv = (float)FBINS / (rmax - rmin);
        const int* cdf = (const int*)(wsf + WS_CDF_OFF);
        const float* binned = wsf + WS_BINNED_OFF;
        const float t = fmaf(width, kp1, lo);
        int fb = (int)floorf((t - rmin) * finv);
        int a  = min(max(fb - 2, 0), FBINS);
        int bb = min(max(fb + 3, 0), FBINS);
        int ia = cdf[a], ib = cdf[bb];
        C = ia;
        for (int i = ia; i < ib; i += 4) {
            float x0 = binned[i];
            float x1 = (i + 1 < ib) ? binned[i + 1] : 3.0e38f;
            float x2 = (i + 2 < ib) ? binned[i + 2] : 3.0e38f;
            float x3 = (i + 3 < ib) ? binned[i + 3] : 3.0e38f;
            C += ((x0 - lo) / width < kp1) ? 1 : 0;
            C += ((x1 - lo) / width < kp1) ? 1 : 0;
            C += ((x2 - lo) / width < kp1) ? 1 : 0;
            C += ((x3 - lo) / width < kp1) ? 1 : 0;
        }
    }
    int Cprev = __shfl_up(C, 1);
    if (lane == 0) Cprev = 0;
    if (act) p = (float)(C - Cprev) * inv + EPSF;

    float P = p, Q = q;
    #pragma unroll
    for (int off = 32; off > 0; off >>= 1) {
        P += __shfl_xor(P, off);
        Q += __shfl_xor(Q, off);
    }
    float term = 0.0f;
    if (act) {
        const float pn = p / P;
        const float qn = q / Q;
        term = pn * logf(pn / qn);
    }
    #pragma unroll
    for (int off = 32; off > 0; off >>= 1) term += __shfl_xor(term, off);
    if (lane == 0) kl_out[b] = term;

    if (lane < HDIM) {
        float acc = b2[lane];
        #pragma unroll
        for (int t2 = 0; t2 < HDIM; ++t2) {
            float h = fmaxf(fmaf(term, w1[t2], b1[t2]), 0.0f);
            acc = fmaf(h, w2[lane * HDIM + t2], acc);
        }
        enc_out[(size_t)b * HDIM + lane] = acc;
    }
}

extern "C" void kernel_launch(void* const* d_in, const int* in_sizes, int n_in,
                              void* d_out, int out_size, void* d_ws, size_t ws_size,
                              hipStream_t stream) {
    const float* cur = (const float*)d_in[0];
    const float* ref = (const float*)d_in[1];
    const float* w1  = (const float*)d_in[2];
    const float* b1  = (const float*)d_in[3];
    const float* w2  = (const float*)d_in[4];
    const float* b2  = (const float*)d_in[5];
    float* out = (float*)d_out;           // [0, B) = kl ; [B, B + B*H) = encoded
    float* wsf = (float*)d_ws;

    ref_cdf_kernel<<<1, 256, 0, stream>>>(ref, wsf);
    kl_wave_kernel<<<B_ROWS, 64, 0, stream>>>(
        cur, wsf, w1, b1, w2, b2, out, out + B_ROWS);
}